// Round 7
// baseline (91.603 us; speedup 1.0000x reference)
//
#include <hip/hip_runtime.h>
#include <hip/hip_cooperative_groups.h>
#include <math.h>

namespace cg = cooperative_groups;

#define NIMG 24        // B*C = 8*3
#define H    256
#define W    256
#define NPIX (H * W)
#define NROWS (NIMG * H)           // 6144
#define GRID 256
#define BLK  1024
#define WPB  (BLK / 64)            // 16 waves per block
#define NWAVE (GRID * WPB)         // 4096
#define CPB  32                    // columns per phase-2 tile
#define NTILE (NIMG * (W / CPB))   // 192 tile tasks
#define BIGF 1.0e6f

// ---------------------------------------------------------------------------
// Wave-level inclusive max scans (64 lanes)
// ---------------------------------------------------------------------------
__device__ __forceinline__ float wscan_fwd_max(float v, int lane) {
#pragma unroll
    for (int off = 1; off < 64; off <<= 1) {
        float u = __shfl_up(v, off, 64);
        if (lane >= off) v = fmaxf(v, u);
    }
    return v;
}
__device__ __forceinline__ float wscan_rev_max(float v, int lane) {
#pragma unroll
    for (int off = 1; off < 64; off <<= 1) {
        float u = __shfl_down(v, off, 64);
        if (lane + off < 64) v = fmaxf(v, u);
    }
    return v;
}

// ---------------------------------------------------------------------------
// Single cooperative kernel (r6 lesson: 3 graph nodes cost ~25us of launch
// overhead; r5 lesson: cooperative fusion needs 1024-thr blocks for latency
// hiding + tile-staged coalesced reads to avoid 4x fetch amplification).
//  phase 1: row EDT (wave per row, lane owns 4 cols) -> f = g_pos - g_neg
//           (one float encodes both polarities; sign = pixel polarity)
//  grid.sync()
//  phase 2: 192 (img, 32-col) tile tasks; full 256x32 f-tile staged in LDS
//           via coalesced row-segment float4 loads; window-bounded exact
//           min-plus  D2[i] = min_{|k-i|<=g[i]} g_m[k]^2 + (i-k)^2
//           (minimizer must satisfy |i-k| <= g[i] since k=i gives g[i]^2);
//           all finite terms exact fp32 ints -> bitwise equal to full scan.
//           + sigmoid(pred)*d, per-block double partial (fixed order).
//  grid.sync()
//  phase 3: block 0 reduces 192 partials -> mean -> out.
// No atomics anywhere (r3 lesson: same-line device atomics ~23ns each).
// ---------------------------------------------------------------------------
__global__ void boundary_fused_kernel(const int* __restrict__ tgt,
                                      const float* __restrict__ pred,
                                      float* __restrict__ fbuf,
                                      double* __restrict__ partials,
                                      float* __restrict__ out) {
    cg::grid_group grid = cg::this_grid();
    const int t    = threadIdx.x;
    const int lane = t & 63;
    const int wid  = t >> 6;
    const int bid  = blockIdx.x;

    // ---------------- phase 1: row EDT ----------------
    {
        const float c0 = (float)(lane << 2);
        const float c1 = c0 + 1.0f, c2 = c0 + 2.0f, c3 = c0 + 3.0f;
        for (int gw = bid * WPB + wid; gw < NROWS; gw += NWAVE) {
            const int img = gw >> 8;
            const int row = gw & 255;
            const int4 tv = ((const int4*)(tgt + (img << 16) + (row << 8)))[lane];

            auto polarity = [&](bool z0, bool z1, bool z2, bool z3) -> float4 {
                float a0 = z0 ? c0 : -BIGF;
                float a1 = fmaxf(z1 ? c1 : -BIGF, a0);
                float a2 = fmaxf(z2 ? c2 : -BIGF, a1);
                float a3 = fmaxf(z3 ? c3 : -BIGF, a2);
                float sm = wscan_fwd_max(a3, lane);
                float ex = __shfl_up(sm, 1, 64);
                if (lane == 0) ex = -BIGF;
                float b3 = z3 ? -c3 : -BIGF;
                float b2 = fmaxf(z2 ? -c2 : -BIGF, b3);
                float b1 = fmaxf(z1 ? -c1 : -BIGF, b2);
                float b0 = fmaxf(z0 ? -c0 : -BIGF, b1);
                float sr  = wscan_rev_max(b0, lane);
                float exr = __shfl_down(sr, 1, 64);
                if (lane == 63) exr = -BIGF;

                float l0 = fmaxf(ex, a0), l1 = fmaxf(ex, a1);
                float l2 = fmaxf(ex, a2), l3 = fmaxf(ex, a3);
                float n0 = fmaxf(exr, b0), n1 = fmaxf(exr, b1);
                float n2 = fmaxf(exr, b2), n3 = fmaxf(exr, b3);

                float4 g;
                g.x = fminf(fminf(c0 - l0, -n0 - c0), BIGF);
                g.y = fminf(fminf(c1 - l1, -n1 - c1), BIGF);
                g.z = fminf(fminf(c2 - l2, -n2 - c2), BIGF);
                g.w = fminf(fminf(c3 - l3, -n3 - c3), BIGF);
                return g;
            };

            const float4 gp = polarity(tv.x == 0, tv.y == 0, tv.z == 0, tv.w == 0);
            const float4 gn = polarity(tv.x != 0, tv.y != 0, tv.z != 0, tv.w != 0);
            float4 o;
            o.x = gp.x - gn.x;  o.y = gp.y - gn.y;
            o.z = gp.z - gn.z;  o.w = gp.w - gn.w;
            ((float4*)(fbuf + (img << 16) + (row << 8)))[lane] = o;
        }
    }

    grid.sync();

    // ---------------- phase 2: column min-plus ----------------
    __shared__ float sf[H][CPB];          // 32 KB
    __shared__ int nonempty;
    __shared__ double wsum[WPB];

    if (bid < NTILE) {
        const int img = bid >> 3;
        const int j0  = (bid & 7) << 5;
        if (t == 0) nonempty = 0;

        bool myne = false;
#pragma unroll
        for (int s = 0; s < 2; ++s) {
            const int idx = t + (s << 10);    // 0..2047 float4-chunks
            const int row = idx >> 3;
            const int q   = (idx & 7) << 2;   // float offset within row
            const float4 v = *(const float4*)(fbuf + (img << 16) + (row << 8) + j0 + q);
            sf[row][q] = v.x; sf[row][q + 1] = v.y;
            sf[row][q + 2] = v.z; sf[row][q + 3] = v.w;
            myne = myne || (v.x != -BIGF) || (v.y != -BIGF) ||
                           (v.z != -BIGF) || (v.w != -BIGF);
        }
        __syncthreads();                      // tile ready; nonempty=0 ordered
        if (myne) nonempty = 1;               // benign race, all write 1
        __syncthreads();
        const int flag = nonempty;

        const int c  = t & 31;                // own column within tile
        const int r0 = (t >> 5) << 3;         // own 8-row band
        double acc = 0.0;
#pragma unroll
        for (int ii = 0; ii < 8; ++ii) {
            const int i = r0 + ii;
            const float fv = sf[i][c];
            const bool  m  = fv > 0.0f;       // sign(f) = pixel polarity
            const float sgn = m ? 1.0f : -1.0f;
            const float gi = fabsf(fv);
            const int  gii = (int)gi;
            int lo = i - gii; lo = lo > 0 ? lo : 0;
            int hi = i + gii; hi = hi < (H - 1) ? hi : (H - 1);

            float dm = 3.0e38f;
            float dk = (float)(i - lo);
            for (int k = lo; k <= hi; ++k) {
                const float g = fmaxf(sgn * sf[k][c], 0.0f);  // needed polarity
                dm = fminf(dm, fmaf(g, g, dk * dk));
                dk -= 1.0f;
            }

            float d = m ? sqrtf(dm) : -sqrtf(dm);
            if (!flag) d = 0.0f;
            const float p = pred[(img << 16) + (i << 8) + j0 + c];
            const float sig = 1.0f / (1.0f + expf(-p));
            acc += (double)sig * (double)d;
        }

        // wave reduce (double), then 16 wave sums -> per-block partial
#pragma unroll
        for (int off = 32; off > 0; off >>= 1) acc += __shfl_down(acc, off, 64);
        if (lane == 0) wsum[wid] = acc;
        __syncthreads();
        if (t == 0) {
            double s = 0.0;
#pragma unroll
            for (int w = 0; w < WPB; ++w) s += wsum[w];
            partials[bid] = s;
        }
    }

    grid.sync();

    // ---------------- phase 3: final reduction ----------------
    if (bid == 0 && t < 256) {
        __shared__ double sred[256];
        sred[t] = (t < NTILE) ? partials[t] : 0.0;
        __syncthreads();
#pragma unroll
        for (int off = 128; off > 0; off >>= 1) {
            if (t < off) sred[t] += sred[t + off];
            __syncthreads();
        }
        if (t == 0) out[0] = (float)(sred[0] / (double)(NIMG * NPIX));
    }
}

extern "C" void kernel_launch(void* const* d_in, const int* in_sizes, int n_in,
                              void* d_out, int out_size, void* d_ws, size_t ws_size,
                              hipStream_t stream) {
    const float* pred = (const float*)d_in[0];
    const int*   tgt  = (const int*)d_in[1];
    float* out = (float*)d_out;

    char* ws = (char*)d_ws;
    const size_t fbytes = (size_t)NIMG * NPIX * sizeof(float);   // 6,291,456 B
    float*  fbuf     = (float*)(ws);
    double* partials = (double*)(ws + fbytes);                   // 192 * 8 B

    void* args[] = { (void*)&tgt, (void*)&pred, (void*)&fbuf,
                     (void*)&partials, (void*)&out };
    hipLaunchCooperativeKernel((const void*)boundary_fused_kernel,
                               dim3(GRID), dim3(BLK), args, 0, stream);
}

// Round 9
// 55.042 us; speedup vs baseline: 1.6642x; 1.6642x over previous
//
#include <hip/hip_runtime.h>
#include <math.h>

#define NIMG 24        // B*C = 8*3
#define H    256
#define W    256
#define NPIX (H * W)
#define CPB  32                  // columns per block tile
#define GRID2 (NIMG * (W / CPB)) // 192 blocks
#define BLKT 512                 // 8 waves
#define WPB  (BLKT / 64)
#define RPW  (H / WPB)           // 32 rows per wave in phase A
#define BIGF 1.0e6f

// ---------------------------------------------------------------------------
// Wave-level inclusive max scans (64 lanes)
// ---------------------------------------------------------------------------
__device__ __forceinline__ float wscan_fwd_max(float v, int lane) {
#pragma unroll
    for (int off = 1; off < 64; off <<= 1) {
        float u = __shfl_up(v, off, 64);
        if (lane >= off) v = fmaxf(v, u);
    }
    return v;
}
__device__ __forceinline__ float wscan_rev_max(float v, int lane) {
#pragma unroll
    for (int off = 1; off < 64; off <<= 1) {
        float u = __shfl_down(v, off, 64);
        if (lane + off < 64) v = fmaxf(v, u);
    }
    return v;
}

// ---------------------------------------------------------------------------
// Main kernel (r8 structure, ticket finalize removed — r8 lesson: a
// monotonic ticket with unknown poisoned start picks ONE winner per call
// but not the LAST arriver; last-arrival detection needs a known start).
//
// Block = (img, 32-col tile). Phase A: all 8 waves run the row EDT over ALL
// 256 rows of the image (wave-scan, lane owns 4 cols) — 8x redundant but
// wall-time-invariant — storing only this block's 32-col slice of
// f = g_pos - g_neg in LDS (exactly one polarity nonzero per pixel; sign =
// polarity). Full-image scan also yields the EXACT mask-empty flag.
// Phase B: window-bounded exact min-plus per column (minimizer satisfies
// |i-k| <= g[i] since k=i gives g[i]^2; all finite terms exact fp32 ints ->
// bitwise equal to reference's full scan), + sigmoid(pred)*d, fixed-order
// double reduction -> partials[bid]. No atomics, no fences.
// ---------------------------------------------------------------------------
__global__ __launch_bounds__(BLKT)
void boundary_main_kernel(const int* __restrict__ tgt,
                          const float* __restrict__ pred,
                          double* __restrict__ partials) {
    const int bid  = blockIdx.x;          // img*8 + jg
    const int img  = bid >> 3;
    const int j0   = (bid & 7) << 5;
    const int t    = threadIdx.x;
    const int lane = t & 63;
    const int wid  = t >> 6;

    __shared__ float sf[H][CPB];          // 32 KB signed-field tile
    __shared__ double wsum[WPB];
    __shared__ int nonempty;
    if (t == 0) nonempty = 0;
    __syncthreads();

    // ---------------- phase A: row EDT (full image, keep 32-col slice) ----
    const float c0 = (float)(lane << 2);
    const float c1 = c0 + 1.0f, c2 = c0 + 2.0f, c3 = c0 + 3.0f;
    const int  cb   = (lane << 2) - j0;   // column within tile, if mine
    const bool mine = (cb >= 0) && (cb < CPB);
    int anynz = 0;

    for (int s = 0; s < RPW; ++s) {
        const int row = wid * RPW + s;
        const int4 tv = ((const int4*)(tgt + (img << 16) + (row << 8)))[lane];
        anynz |= (tv.x | tv.y | tv.z | tv.w);

        auto polarity = [&](bool z0, bool z1, bool z2, bool z3) -> float4 {
            float a0 = z0 ? c0 : -BIGF;
            float a1 = fmaxf(z1 ? c1 : -BIGF, a0);
            float a2 = fmaxf(z2 ? c2 : -BIGF, a1);
            float a3 = fmaxf(z3 ? c3 : -BIGF, a2);
            float sm = wscan_fwd_max(a3, lane);
            float ex = __shfl_up(sm, 1, 64);
            if (lane == 0) ex = -BIGF;
            float b3 = z3 ? -c3 : -BIGF;
            float b2 = fmaxf(z2 ? -c2 : -BIGF, b3);
            float b1 = fmaxf(z1 ? -c1 : -BIGF, b2);
            float b0 = fmaxf(z0 ? -c0 : -BIGF, b1);
            float sr  = wscan_rev_max(b0, lane);
            float exr = __shfl_down(sr, 1, 64);
            if (lane == 63) exr = -BIGF;

            float l0 = fmaxf(ex, a0), l1 = fmaxf(ex, a1);
            float l2 = fmaxf(ex, a2), l3 = fmaxf(ex, a3);
            float n0 = fmaxf(exr, b0), n1 = fmaxf(exr, b1);
            float n2 = fmaxf(exr, b2), n3 = fmaxf(exr, b3);

            float4 g;
            g.x = fminf(fminf(c0 - l0, -n0 - c0), BIGF);
            g.y = fminf(fminf(c1 - l1, -n1 - c1), BIGF);
            g.z = fminf(fminf(c2 - l2, -n2 - c2), BIGF);
            g.w = fminf(fminf(c3 - l3, -n3 - c3), BIGF);
            return g;
        };

        const float4 gp = polarity(tv.x == 0, tv.y == 0, tv.z == 0, tv.w == 0);
        const float4 gn = polarity(tv.x != 0, tv.y != 0, tv.z != 0, tv.w != 0);
        if (mine) {
            float4 o;
            o.x = gp.x - gn.x;  o.y = gp.y - gn.y;
            o.z = gp.z - gn.z;  o.w = gp.w - gn.w;
            *(float4*)&sf[row][cb] = o;
        }
    }
    if (__any(anynz != 0)) {
        if (lane == 0) nonempty = 1;      // benign race, all write 1
    }
    __syncthreads();
    const int flag = nonempty;            // exact mask.sum()!=0 (full image)

    // ---------------- phase B: column min-plus ----------------
    const int c  = t & 31;                // own column within tile
    const int r0 = (t >> 5) << 4;         // own 16-row band
    double acc = 0.0;
#pragma unroll 4
    for (int ii = 0; ii < 16; ++ii) {
        const int i = r0 + ii;
        const float fv = sf[i][c];
        const bool  m  = fv > 0.0f;       // sign(f) = pixel polarity
        const float sgn = m ? 1.0f : -1.0f;
        const float gi = fabsf(fv);
        const int  gii = (int)gi;
        int lo = i - gii; lo = lo > 0 ? lo : 0;
        int hi = i + gii; hi = hi < (H - 1) ? hi : (H - 1);

        float dm = 3.0e38f;
        float dk = (float)(i - lo);
        for (int k = lo; k <= hi; ++k) {
            const float g = fmaxf(sgn * sf[k][c], 0.0f);  // needed polarity
            dm = fminf(dm, fmaf(g, g, dk * dk));
            dk -= 1.0f;
        }

        float d = m ? sqrtf(dm) : -sqrtf(dm);
        if (!flag) d = 0.0f;
        const float p = pred[(img << 16) + (i << 8) + j0 + c];
        const float sig = 1.0f / (1.0f + expf(-p));
        acc += (double)sig * (double)d;
    }

    // wave reduce (double, fixed order), 8 wave sums -> block partial
#pragma unroll
    for (int off = 32; off > 0; off >>= 1) acc += __shfl_down(acc, off, 64);
    if (lane == 0) wsum[wid] = acc;
    __syncthreads();
    if (t == 0) {
        double s = 0.0;
#pragma unroll
        for (int w = 0; w < WPB; ++w) s += wsum[w];
        partials[bid] = s;
    }
}

// ---------------------------------------------------------------------------
// Finalize: deterministic fixed-order sum of 192 partials -> mean -> fp32
// ---------------------------------------------------------------------------
__global__ void finalize_kernel(const double* __restrict__ partials,
                                float* __restrict__ out) {
    const int t = threadIdx.x;            // 64 threads
    double a = partials[t] + partials[t + 64] + partials[t + 128];
#pragma unroll
    for (int off = 32; off > 0; off >>= 1) a += __shfl_down(a, off, 64);
    if (t == 0) out[0] = (float)(a / (double)(NIMG * NPIX));
}

extern "C" void kernel_launch(void* const* d_in, const int* in_sizes, int n_in,
                              void* d_out, int out_size, void* d_ws, size_t ws_size,
                              hipStream_t stream) {
    const float* pred = (const float*)d_in[0];
    const int*   tgt  = (const int*)d_in[1];
    float* out = (float*)d_out;

    double* partials = (double*)d_ws;     // 192 * 8 B

    boundary_main_kernel<<<GRID2, BLKT, 0, stream>>>(tgt, pred, partials);
    finalize_kernel<<<1, 64, 0, stream>>>(partials, out);
}

// Round 10
// 28.326 us; speedup vs baseline: 3.2339x; 1.9432x over previous
//
#include <hip/hip_runtime.h>
#include <math.h>

#define NIMG 24        // B*C = 8*3
#define H    256
#define W    256
#define NPIX (H * W)
#define NROWS (NIMG * H)
#define CPB  16                   // columns per pass-2 tile
#define GRID2 (NIMG * (W / CPB))  // 384 blocks
#define NPART GRID2
#define BIGF 1.0e6f
#define CAPTHR (-5.0e5f)          // f below this => row-has-no-foreground marker

// ---------------------------------------------------------------------------
// Wave-level scans (64 lanes)
// ---------------------------------------------------------------------------
__device__ __forceinline__ float wscan_fwd_max(float v, int lane) {
#pragma unroll
    for (int off = 1; off < 64; off <<= 1) {
        float u = __shfl_up(v, off, 64);
        if (lane >= off) v = fmaxf(v, u);
    }
    return v;
}
__device__ __forceinline__ float wscan_rev_min(float v, int lane) {
#pragma unroll
    for (int off = 1; off < 64; off <<= 1) {
        float u = __shfl_down(v, off, 64);
        if (lane + off < 64) v = fminf(v, u);
    }
    return v;
}

// ---------------------------------------------------------------------------
// Pass 1: one WAVE per row (lane owns 4 cols). KEY REDUCTION (r9 lesson:
// wave-scan latency is the cost — halve the scans): only the own-polarity
// distance survives in f = +-g, and that equals the distance to the nearest
// CLASS CHANGE in the row. So ONE fwd cummax of change positions (-> run
// start s) + ONE rev cummin (-> next change n) replace the four polarity
// scans:  dist_prev = c - s + 1  (== reference col - last, exact)
//         dist_next = n - c      (== reference nxt - col, exact)
//         g = min(dist_prev, dist_next, BIG); f = (t!=0) ? g : -g.
// Cap values land on exactly the reference's numbers (1e6, 1e6-c).
// ---------------------------------------------------------------------------
__global__ void edt_rows_kernel(const int* __restrict__ tgt,
                                float* __restrict__ f) {
    const int tid  = blockIdx.x * 256 + threadIdx.x;
    const int gw   = tid >> 6;          // global wave id == row id
    const int lane = tid & 63;
    const int img  = gw >> 8;
    const int row  = gw & 255;

    const int4 tv = ((const int4*)(tgt + (img << 16) + (row << 8)))[lane];
    const float c0 = (float)(lane << 2);
    const float c1 = c0 + 1.0f, c2 = c0 + 2.0f, c3 = c0 + 3.0f;

    // class-change flags (index 0 has no predecessor -> false)
    const int prevw = __shfl_up(tv.w, 1, 64);
    const bool ch0 = (lane > 0) && ((tv.x != 0) != (prevw != 0));
    const bool ch1 = (tv.y != 0) != (tv.x != 0);
    const bool ch2 = (tv.z != 0) != (tv.y != 0);
    const bool ch3 = (tv.w != 0) != (tv.z != 0);

    // fwd inclusive cummax of (ch ? c : -BIG)  -> run start s
    const float a0 = ch0 ? c0 : -BIGF;
    const float a1 = ch1 ? c1 : a0;     // c1 > any earlier candidate
    const float a2 = ch2 ? c2 : a1;
    const float a3 = ch3 ? c3 : a2;
    const float sm = wscan_fwd_max(a3, lane);
    float ex = __shfl_up(sm, 1, 64);
    if (lane == 0) ex = -BIGF;
    const float s0 = fmaxf(ex, a0);
    const float s1 = fmaxf(ex, a1);
    const float s2 = fmaxf(ex, a2);
    const float s3 = fmaxf(ex, a3);

    // rev inclusive cummin of (ch ? c : BIG) -> next change (shift by one)
    const float rb3 = ch3 ? c3 : BIGF;
    const float rb2 = ch2 ? c2 : rb3;
    const float rb1 = ch1 ? c1 : rb2;
    const float rb0 = ch0 ? c0 : rb1;
    const float sr  = wscan_rev_min(rb0, lane);
    float exr = __shfl_down(sr, 1, 64);
    if (lane == 63) exr = BIGF;
    const float n0 = fminf(rb1, exr);   // first change at index > c0
    const float n1 = fminf(rb2, exr);
    const float n2 = fminf(rb3, exr);
    const float n3 = exr;

    const float g0 = fminf(fminf(c0 - s0 + 1.0f, n0 - c0), BIGF);
    const float g1 = fminf(fminf(c1 - s1 + 1.0f, n1 - c1), BIGF);
    const float g2 = fminf(fminf(c2 - s2 + 1.0f, n2 - c2), BIGF);
    const float g3 = fminf(fminf(c3 - s3 + 1.0f, n3 - c3), BIGF);

    float4 o;
    o.x = (tv.x != 0) ? g0 : -g0;
    o.y = (tv.y != 0) ? g1 : -g1;
    o.z = (tv.z != 0) ? g2 : -g2;
    o.w = (tv.w != 0) ? g3 : -g3;
    ((float4*)(f + (img << 16) + (row << 8)))[lane] = o;
}

// ---------------------------------------------------------------------------
// Pass 2: block = (img, 16-col group), 384 blocks x 256 thr. Tile staged
// with exact 64B-line row segments (zero fetch amplification, r5/r6
// lesson). Window-bounded exact min-plus (minimizer satisfies |i-k|<=g[i]
// since k=i gives g[i]^2; all finite terms exact fp32 ints; separate
// mul+add matches reference rounding even for capped g). Empty-mask flag
// from cap markers: mask empty <=> every row has no foreground <=> all
// f in tile < -5e5 (capped values are >= 999745; real ones <= 256).
// ---------------------------------------------------------------------------
__global__ void edt_cols_kernel(const float* __restrict__ f,
                                const float* __restrict__ pred,
                                double* __restrict__ partials) {
    const int bid  = blockIdx.x;          // img*16 + grp
    const int img  = bid >> 4;
    const int j0   = (bid & 15) << 4;
    const int t    = threadIdx.x;
    const int lane = t & 63;
    const int wid  = t >> 6;

    __shared__ float sf[H][CPB];          // 16 KB
    __shared__ double wsum[4];
    __shared__ int nonempty;
    if (t == 0) nonempty = 0;
    __syncthreads();

    bool myne = false;
#pragma unroll
    for (int s = 0; s < 4; ++s) {
        const int id  = t + (s << 8);     // 0..1023 float4-chunks
        const int row = id >> 2;
        const int q   = (id & 3) << 2;    // float offset within 16-col row
        const float4 v = *(const float4*)(f + (img << 16) + (row << 8) + j0 + q);
        *(float4*)&sf[row][q] = v;
        myne = myne || (v.x > CAPTHR) || (v.y > CAPTHR) ||
                       (v.z > CAPTHR) || (v.w > CAPTHR);
    }
    if (myne) nonempty = 1;               // benign race, all write 1
    __syncthreads();
    const int flag = nonempty;            // exact: mask.sum() != 0

    const int c  = t & 15;                // own column within tile
    const int r0 = (t >> 4) << 4;         // own 16-row band
    double acc = 0.0;
#pragma unroll 4
    for (int ii = 0; ii < 16; ++ii) {
        const int i = r0 + ii;
        const float fv = sf[i][c];
        const bool  m  = fv > 0.0f;       // sign(f) = pixel polarity
        const float sgn = m ? 1.0f : -1.0f;
        const float gi = fabsf(fv);
        const int  gii = (int)gi;
        int lo = i - gii; lo = lo > 0 ? lo : 0;
        int hi = i + gii; hi = hi < (H - 1) ? hi : (H - 1);

        float dm = 3.0e38f;
        float dk = (float)(i - lo);
        for (int k = lo; k <= hi; ++k) {
            const float g = fmaxf(sgn * sf[k][c], 0.0f);  // needed polarity
            dm = fminf(dm, g * g + dk * dk);
            dk -= 1.0f;
        }

        float d = m ? sqrtf(dm) : -sqrtf(dm);
        if (!flag) d = 0.0f;
        const float p = pred[(img << 16) + (i << 8) + j0 + c];
        const float sig = 1.0f / (1.0f + expf(-p));
        acc += (double)sig * (double)d;
    }

    // wave reduce (double, fixed order), 4 wave sums -> block partial
#pragma unroll
    for (int off = 32; off > 0; off >>= 1) acc += __shfl_down(acc, off, 64);
    if (lane == 0) wsum[wid] = acc;
    __syncthreads();
    if (t == 0) partials[bid] = (wsum[0] + wsum[1]) + (wsum[2] + wsum[3]);
}

// ---------------------------------------------------------------------------
// Finalize: deterministic fixed-order sum of 384 partials -> mean -> fp32
// ---------------------------------------------------------------------------
__global__ void finalize_kernel(const double* __restrict__ partials,
                                float* __restrict__ out) {
    const int t = threadIdx.x;            // 64 threads
    double a = 0.0;
#pragma unroll
    for (int s = 0; s < NPART / 64; ++s) a += partials[t + (s << 6)];
#pragma unroll
    for (int off = 32; off > 0; off >>= 1) a += __shfl_down(a, off, 64);
    if (t == 0) out[0] = (float)(a / (double)(NIMG * NPIX));
}

extern "C" void kernel_launch(void* const* d_in, const int* in_sizes, int n_in,
                              void* d_out, int out_size, void* d_ws, size_t ws_size,
                              hipStream_t stream) {
    const float* pred = (const float*)d_in[0];
    const int*   tgt  = (const int*)d_in[1];
    float* out = (float*)d_out;

    char* ws = (char*)d_ws;
    const size_t fbytes = (size_t)NIMG * NPIX * sizeof(float);   // 6,291,456 B
    float*  fbuf     = (float*)(ws);
    double* partials = (double*)(ws + fbytes);                   // 384 * 8 B

    edt_rows_kernel<<<NROWS / 4, 256, 0, stream>>>(tgt, fbuf);
    edt_cols_kernel<<<GRID2, 256, 0, stream>>>(fbuf, pred, partials);
    finalize_kernel<<<1, 64, 0, stream>>>(partials, out);
}

// Round 11
// 25.577 us; speedup vs baseline: 3.5814x; 1.1075x over previous
//
#include <hip/hip_runtime.h>
#include <math.h>

#define NIMG 24        // B*C = 8*3
#define H    256
#define W    256
#define NPIX (H * W)
#define NROWS (NIMG * H)
#define CPB  8                    // columns per pass-2 tile
#define LDP  9                    // padded LDS row stride (2-way banks only)
#define GRID2 (NIMG * (W / CPB))  // 768 blocks
#define NPART GRID2
#define BIGI 1000000
#define BIGF 1.0e6f
#define CAPTHR (-5.0e5f)          // f below this => row-has-no-foreground marker

// ---------------------------------------------------------------------------
// Pass 1: one WAVE per row (lane owns 4 cols). r10's class-change run
// formulation (validated bit-exact) with the wave SCAN replaced by O(1)
// ballot+indexed-shfl (r10 lesson: the 12-step dependent shuffle chain was
// the latency cost):
//   mask = ballot(lane has a change); prev-change lane = 63-clz(low bits),
//   next-change lane = ctz(high bits); one shfl fetches that lane's
//   last/first change position. Same exact integer positions:
//     dist_prev = c - s + 1  (== reference col - last)
//     dist_next = n - c      (== reference nxt - col)
//     g = min(dist_prev, dist_next, BIG); f = (t!=0) ? g : -g.
// ---------------------------------------------------------------------------
__global__ void edt_rows_kernel(const int* __restrict__ tgt,
                                float* __restrict__ f) {
    const int tid  = blockIdx.x * 256 + threadIdx.x;
    const int gw   = tid >> 6;          // global wave id == row id
    const int lane = tid & 63;
    const int img  = gw >> 8;
    const int row  = gw & 255;

    const int4 tv = ((const int4*)(tgt + (img << 16) + (row << 8)))[lane];
    const int c0 = lane << 2;

    // class-change flags (global index 0 has no predecessor -> false)
    const int prevw = __shfl_up(tv.w, 1, 64);
    const bool ch0 = (lane > 0) && ((tv.x != 0) != (prevw != 0));
    const bool ch1 = (tv.y != 0) != (tv.x != 0);
    const bool ch2 = (tv.z != 0) != (tv.y != 0);
    const bool ch3 = (tv.w != 0) != (tv.z != 0);

    // within-lane prefix (last change <= c_i) and suffix (first change >= c_i)
    const int a0 = ch0 ? c0     : -BIGI;
    const int a1 = ch1 ? c0 + 1 : a0;
    const int a2 = ch2 ? c0 + 2 : a1;
    const int a3 = ch3 ? c0 + 3 : a2;     // lane's last change pos (or -BIGI)
    const int rb3 = ch3 ? c0 + 3 : BIGI;
    const int rb2 = ch2 ? c0 + 2 : rb3;
    const int rb1 = ch1 ? c0 + 1 : rb2;
    const int rb0 = ch0 ? c0     : rb1;   // lane's first change pos (or BIGI)

    // O(1) cross-lane: ballot + clz/ctz + one indexed shfl each way
    const unsigned long long mask = __ballot(ch0 | ch1 | ch2 | ch3);
    const unsigned long long lowm = mask & ((1ULL << lane) - 1ULL);
    const unsigned long long him  = (lane < 63) ? (mask >> (lane + 1)) : 0ULL;

    const int plane = 63 - __builtin_clzll(lowm | 1ULL);        // valid if lowm!=0
    const int sh_a  = __shfl(a3, plane & 63, 64);
    const int ex    = (lowm != 0ULL) ? sh_a : -BIGI;            // last change < c0

    const int qlane = lane + 1 +
        (int)__builtin_ctzll(him | 0x8000000000000000ULL);      // valid if him!=0
    const int sh_r  = __shfl(rb0, qlane & 63, 64);
    const int exr   = (him != 0ULL) ? sh_r : BIGI;              // first change > c3

    const int s0 = (ex > a0) ? ex : a0;
    const int s1 = (ex > a1) ? ex : a1;
    const int s2 = (ex > a2) ? ex : a2;
    const int s3 = (ex > a3) ? ex : a3;
    const int n0 = (rb1 < exr) ? rb1 : exr;
    const int n1 = (rb2 < exr) ? rb2 : exr;
    const int n2 = (rb3 < exr) ? rb3 : exr;
    const int n3 = exr;

    auto gcalc = [](int c, int s, int n) -> int {
        int dp = c - s + 1;
        int dn = n - c;
        int g = dp < dn ? dp : dn;
        return g < BIGI ? g : BIGI;
    };
    const float g0 = (float)gcalc(c0,     s0, n0);
    const float g1 = (float)gcalc(c0 + 1, s1, n1);
    const float g2 = (float)gcalc(c0 + 2, s2, n2);
    const float g3 = (float)gcalc(c0 + 3, s3, n3);

    float4 o;
    o.x = (tv.x != 0) ? g0 : -g0;
    o.y = (tv.y != 0) ? g1 : -g1;
    o.z = (tv.z != 0) ? g2 : -g2;
    o.w = (tv.w != 0) ? g3 : -g3;
    ((float4*)(f + (img << 16) + (row << 8)))[lane] = o;
}

// ---------------------------------------------------------------------------
// Pass 2: block = (img, 8-col group), 768 blocks x 256 thr (3 blocks/CU —
// r10 lesson: 384 blocks = 1.5/CU makespan imbalance). Padded LDS tile
// (stride 9 floats -> 8-lane groups land on disjoint/2-way bank sets).
// Window-bounded exact min-plus (minimizer satisfies |i-k| <= g[i] since
// k=i gives g[i]^2; all finite terms exact fp32 ints; separate mul+add
// matches reference rounding for capped g). Empty-mask flag from cap
// markers: mask empty <=> all f in tile < -5e5.
// ---------------------------------------------------------------------------
__global__ void edt_cols_kernel(const float* __restrict__ f,
                                const float* __restrict__ pred,
                                double* __restrict__ partials) {
    const int bid  = blockIdx.x;          // img*32 + grp
    const int img  = bid >> 5;
    const int j0   = (bid & 31) << 3;
    const int t    = threadIdx.x;
    const int lane = t & 63;
    const int wid  = t >> 6;

    __shared__ float sf[H][LDP];          // 9 KB
    __shared__ double wsum[4];
    __shared__ int nonempty;
    if (t == 0) nonempty = 0;
    __syncthreads();

    bool myne = false;
#pragma unroll
    for (int s = 0; s < 2; ++s) {
        const int id  = t + (s << 8);     // 0..511 float4-chunks
        const int row = id >> 1;
        const int q   = (id & 1) << 2;    // float offset within 8-col row
        const float4 v = *(const float4*)(f + (img << 16) + (row << 8) + j0 + q);
        sf[row][q]     = v.x;  sf[row][q + 1] = v.y;
        sf[row][q + 2] = v.z;  sf[row][q + 3] = v.w;
        myne = myne || (v.x > CAPTHR) || (v.y > CAPTHR) ||
                       (v.z > CAPTHR) || (v.w > CAPTHR);
    }
    if (myne) nonempty = 1;               // benign race, all write 1
    __syncthreads();
    const int flag = nonempty;            // exact: mask.sum() != 0

    const int c  = t & 7;                 // own column within tile
    const int r0 = (t >> 3) << 3;         // own 8-row band
    double acc = 0.0;
#pragma unroll
    for (int ii = 0; ii < 8; ++ii) {
        const int i = r0 + ii;
        const float fv = sf[i][c];
        const bool  m  = fv > 0.0f;       // sign(f) = pixel polarity
        const float sgn = m ? 1.0f : -1.0f;
        const float gi = fabsf(fv);
        const int  gii = (int)gi;
        int lo = i - gii; lo = lo > 0 ? lo : 0;
        int hi = i + gii; hi = hi < (H - 1) ? hi : (H - 1);

        float dm = 3.0e38f;
        float dk = (float)(i - lo);
        for (int k = lo; k <= hi; ++k) {
            const float g = fmaxf(sgn * sf[k][c], 0.0f);  // needed polarity
            dm = fminf(dm, g * g + dk * dk);
            dk -= 1.0f;
        }

        float d = m ? sqrtf(dm) : -sqrtf(dm);
        if (!flag) d = 0.0f;
        const float p = pred[(img << 16) + (i << 8) + j0 + c];
        const float sig = 1.0f / (1.0f + expf(-p));
        acc += (double)sig * (double)d;
    }

    // wave reduce (double, fixed order), 4 wave sums -> block partial
#pragma unroll
    for (int off = 32; off > 0; off >>= 1) acc += __shfl_down(acc, off, 64);
    if (lane == 0) wsum[wid] = acc;
    __syncthreads();
    if (t == 0) partials[bid] = (wsum[0] + wsum[1]) + (wsum[2] + wsum[3]);
}

// ---------------------------------------------------------------------------
// Finalize: deterministic fixed-order sum of 768 partials -> mean -> fp32
// ---------------------------------------------------------------------------
__global__ void finalize_kernel(const double* __restrict__ partials,
                                float* __restrict__ out) {
    const int t = threadIdx.x;            // 64 threads
    double a = 0.0;
#pragma unroll
    for (int s = 0; s < NPART / 64; ++s) a += partials[t + (s << 6)];
#pragma unroll
    for (int off = 32; off > 0; off >>= 1) a += __shfl_down(a, off, 64);
    if (t == 0) out[0] = (float)(a / (double)(NIMG * NPIX));
}

extern "C" void kernel_launch(void* const* d_in, const int* in_sizes, int n_in,
                              void* d_out, int out_size, void* d_ws, size_t ws_size,
                              hipStream_t stream) {
    const float* pred = (const float*)d_in[0];
    const int*   tgt  = (const int*)d_in[1];
    float* out = (float*)d_out;

    char* ws = (char*)d_ws;
    const size_t fbytes = (size_t)NIMG * NPIX * sizeof(float);   // 6,291,456 B
    float*  fbuf     = (float*)(ws);
    double* partials = (double*)(ws + fbytes);                   // 768 * 8 B

    edt_rows_kernel<<<NROWS / 4, 256, 0, stream>>>(tgt, fbuf);
    edt_cols_kernel<<<GRID2, 256, 0, stream>>>(fbuf, pred, partials);
    finalize_kernel<<<1, 64, 0, stream>>>(partials, out);
}